// Round 1
// baseline (735.572 us; speedup 1.0000x reference)
//
#include <hip/hip_runtime.h>

#define AS1 __attribute__((address_space(1)))
#define AS3 __attribute__((address_space(3)))

typedef _Float16 f16x8 __attribute__((ext_vector_type(8)));
typedef _Float16 f16x4 __attribute__((ext_vector_type(4)));
typedef _Float16 f16x2 __attribute__((ext_vector_type(2)));
typedef float f32x4 __attribute__((ext_vector_type(4)));

// ---------------------------------------------------------------- helpers
__device__ __forceinline__ float silu_f(float v) { return v / (1.f + expf(-v)); }

__device__ __forceinline__ void gload_lds16(const void* g, void* l) {
    __builtin_amdgcn_global_load_lds((AS1 void*)g, (AS3 void*)l, 16, 0, 0);
}

// ---------------------------------------------------------------- f32 -> f16 convert
__global__ void cvt_f16(const float* __restrict__ in, _Float16* __restrict__ out, int n) {
    int i = (blockIdx.x * blockDim.x + threadIdx.x) * 4;
    if (i >= n) return;
    float4 v = *(const float4*)&in[i];
    f16x4 h = { (_Float16)v.x, (_Float16)v.y, (_Float16)v.z, (_Float16)v.w };
    *(f16x4*)&out[i] = h;
}

// ---------------------------------------------------------------- GEMM: C = A * B^T
// A: (M x K) f16 row-major, B: (N x K) f16 row-major, C: (M x N) f32.
// M,N multiples of 128; K multiple of 32. Grid: (N/128, M/128), 256 threads.
__global__ __launch_bounds__(256) void gemm_bt(const _Float16* __restrict__ A,
                                               const _Float16* __restrict__ B,
                                               float* __restrict__ C, int N, int K) {
    __shared__ _Float16 As[128 * 32];
    __shared__ _Float16 Bs[128 * 32];
    const int tid = threadIdx.x;
    const int rowA0 = blockIdx.y * 128, rowB0 = blockIdx.x * 128;
    const int lane = tid & 63;
    const int wave = tid >> 6;
    const int wr = (wave >> 1) * 64, wc = (wave & 1) * 64;
    const int fr = lane & 15, kof = (lane >> 4) * 8;
    const int sr0 = tid >> 2;          // staging row 0..63
    const int sc0 = (tid & 3) * 8;     // staging col (elems)

    f32x4 zero = {0.f, 0.f, 0.f, 0.f};
    f32x4 acc[4][4];
#pragma unroll
    for (int i = 0; i < 4; i++)
#pragma unroll
        for (int j = 0; j < 4; j++) acc[i][j] = zero;

    const _Float16* Abase = A + (long)(rowA0 + sr0) * K + sc0;
    const _Float16* Bbase = B + (long)(rowB0 + sr0) * K + sc0;
    const long chunk2 = (long)64 * K;

    for (int k0 = 0; k0 < K; k0 += 32) {
        __syncthreads();
        gload_lds16(Abase + k0,          &As[tid * 8]);
        gload_lds16(Abase + k0 + chunk2, &As[2048 + tid * 8]);
        gload_lds16(Bbase + k0,          &Bs[tid * 8]);
        gload_lds16(Bbase + k0 + chunk2, &Bs[2048 + tid * 8]);
        __syncthreads();
        f16x8 af[4], bf[4];
#pragma unroll
        for (int mi = 0; mi < 4; mi++) af[mi] = *(const f16x8*)&As[(wr + mi * 16 + fr) * 32 + kof];
#pragma unroll
        for (int ni = 0; ni < 4; ni++) bf[ni] = *(const f16x8*)&Bs[(wc + ni * 16 + fr) * 32 + kof];
#pragma unroll
        for (int mi = 0; mi < 4; mi++)
#pragma unroll
            for (int ni = 0; ni < 4; ni++)
                acc[mi][ni] = __builtin_amdgcn_mfma_f32_16x16x32_f16(af[mi], bf[ni], acc[mi][ni], 0, 0, 0);
    }
    const int rbase = (lane >> 4) * 4;
#pragma unroll
    for (int mi = 0; mi < 4; mi++)
#pragma unroll
        for (int ni = 0; ni < 4; ni++) {
            int row = rowA0 + wr + mi * 16 + rbase;
            int col = rowB0 + wc + ni * 16 + fr;
#pragma unroll
            for (int r = 0; r < 4; r++)
                C[(long)(row + r) * N + col] = acc[mi][ni][r];
        }
}

// ---------------------------------------------------------------- beta/alpha projections
// grid 1024 (one per s), 256 threads. outputs beta[s][16], alpha[s][16].
__global__ __launch_bounds__(256) void proj_ba(const float* __restrict__ x,
                                               const float* __restrict__ w_beta,
                                               const float* __restrict__ w_alpha,
                                               const float* __restrict__ log_A,
                                               const float* __restrict__ dt_bias,
                                               float* __restrict__ betaB,
                                               float* __restrict__ alphaB) {
    __shared__ float xs[2048];
    const int s = blockIdx.x, tid = threadIdx.x;
    *(float4*)&xs[tid * 8]     = *(const float4*)&x[(long)s * 2048 + tid * 8];
    *(float4*)&xs[tid * 8 + 4] = *(const float4*)&x[(long)s * 2048 + tid * 8 + 4];
    __syncthreads();
    const int o = tid >> 3, j = tid & 7;   // 32 outputs x 8 threads
    const float* w = (o < 16) ? &w_beta[(long)o * 2048] : &w_alpha[(long)(o - 16) * 2048];
    float p = 0.f;
#pragma unroll 4
    for (int i = 0; i < 64; i++) {
        int d = i * 32 + j * 4;
        float4 wv = *(const float4*)&w[d];
        p += xs[d] * wv.x + xs[d + 1] * wv.y + xs[d + 2] * wv.z + xs[d + 3] * wv.w;
    }
    p += __shfl_xor(p, 1); p += __shfl_xor(p, 2); p += __shfl_xor(p, 4);
    if (j == 0) {
        if (o < 16) {
            betaB[s * 16 + o] = 1.f / (1.f + expf(-p));
        } else {
            int h = o - 16;
            float t = p + dt_bias[h];
            float sp = (t > 20.f) ? t : log1pf(expf(t));
            alphaB[s * 16 + h] = expf(-expf(log_A[h]) * sp);
        }
    }
}

// ---------------------------------------------------------------- causal depthwise conv(K=4) + SiLU
__global__ void conv_silu(const float* __restrict__ pre, const float* __restrict__ cw,
                          float* __restrict__ outp) {
    int i = blockIdx.x * blockDim.x + threadIdx.x;  // 1024*4096
    int s = i >> 12, c = i & 4095;
    float4 w = *(const float4*)&cw[c * 4];
    float acc = pre[(long)s * 4096 + c] * w.w;
    if (s >= 1) acc += pre[(long)(s - 1) * 4096 + c] * w.z;
    if (s >= 2) acc += pre[(long)(s - 2) * 4096 + c] * w.y;
    if (s >= 3) acc += pre[(long)(s - 3) * 4096 + c] * w.x;
    outp[i] = silu_f(acc);
}

// ---------------------------------------------------------------- in-place l2 norm of q,k (+ q * dk^-0.5)
// one wave per (s, group); groups: 0..7 = q heads, 8..15 = k heads
__global__ void norm_qk(float* __restrict__ fqkv) {
    int gw = (blockIdx.x * blockDim.x + threadIdx.x) >> 6;
    int lane = threadIdx.x & 63;
    int s = gw >> 4, idx = gw & 15;
    float* base = fqkv + (long)s * 4096 + (idx < 8 ? idx * 128 : 1024 + (idx - 8) * 128);
    float2 v = *(float2*)&base[lane * 2];
    float ss = v.x * v.x + v.y * v.y;
#pragma unroll
    for (int m = 1; m < 64; m <<= 1) ss += __shfl_xor(ss, m);
    float sc = rsqrtf(ss + 1e-6f);
    if (idx < 8) sc *= 0.08838834764831843f;  // 1/sqrt(128), queries only
    v.x *= sc; v.y *= sc;
    *(float2*)&base[lane * 2] = v;
}

// ---------------------------------------------------------------- gated delta rule scan
// Column-parallel: each (h, v) column is an independent 128-dim recurrence.
// Block = 256 thr = 16 columns x 16 lanes; lane owns 8 k-entries of state.
// Grid = 128 blocks = 16 heads x 8 v-blocks.
#define SCT 32
__global__ __launch_bounds__(256) void scan_kernel(const float* __restrict__ fqkv,
                                                   const float* __restrict__ betaB,
                                                   const float* __restrict__ alphaB,
                                                   float* __restrict__ ctx) {
    __shared__ float lk[SCT][128];
    __shared__ float lq[SCT][128];
    __shared__ float lv[SCT][16];
    __shared__ float la[SCT];
    __shared__ float lb[SCT];
    const int tid = threadIdx.x;
    const int h = blockIdx.x >> 3;
    const int vblk = blockIdx.x & 7;
    const int hq = h >> 1;                 // rep=2 head mapping
    const int coll = tid >> 4;             // column within block (0..15)
    const int kg = tid & 15;               // k-group within column
    const int kb = kg * 8;
    const float* qbase = fqkv + hq * 128;
    const float* kbase = fqkv + 1024 + hq * 128;
    const float* vbase = fqkv + 2048 + h * 128 + vblk * 16;
    float S[8];
#pragma unroll
    for (int j = 0; j < 8; j++) S[j] = 0.f;

    for (int s0 = 0; s0 < 1024; s0 += SCT) {
        __syncthreads();
#pragma unroll
        for (int r = 0; r < 16; r++) {
            int e = r * 256 + tid;
            int t = e >> 7, d = e & 127;
            lk[t][d] = kbase[(long)(s0 + t) * 4096 + d];
            lq[t][d] = qbase[(long)(s0 + t) * 4096 + d];
        }
        {
            int t = tid >> 4, vv = tid & 15;
            lv[t][vv] = vbase[(long)(s0 + t) * 4096 + vv];
            int e = tid + 256; t = e >> 4; vv = e & 15;
            lv[t][vv] = vbase[(long)(s0 + t) * 4096 + vv];
        }
        if (tid < SCT) {
            la[tid] = alphaB[(s0 + tid) * 16 + h];
            lb[tid] = betaB[(s0 + tid) * 16 + h];
        }
        __syncthreads();
        for (int t = 0; t < SCT; t++) {
            float at = la[t], bt = lb[t];
            float kk[8], qq[8];
            *(float4*)&kk[0] = *(const float4*)&lk[t][kb];
            *(float4*)&kk[4] = *(const float4*)&lk[t][kb + 4];
            *(float4*)&qq[0] = *(const float4*)&lq[t][kb];
            *(float4*)&qq[4] = *(const float4*)&lq[t][kb + 4];
            float p = 0.f;
#pragma unroll
            for (int j = 0; j < 8; j++) p += kk[j] * S[j];
            p += __shfl_xor(p, 1); p += __shfl_xor(p, 2);
            p += __shfl_xor(p, 4); p += __shfl_xor(p, 8);
            float kv = at * p;                       // k^T (alpha*S_old)
            float u = bt * (lv[t][coll] - kv);
            float o = 0.f;
#pragma unroll
            for (int j = 0; j < 8; j++) {
                S[j] = at * S[j] + kk[j] * u;        // decay + rank-1 update
                o += qq[j] * S[j];
            }
            o += __shfl_xor(o, 1); o += __shfl_xor(o, 2);
            o += __shfl_xor(o, 4); o += __shfl_xor(o, 8);
            if (kg == 0)
                ctx[(long)(s0 + t) * 2048 + h * 128 + vblk * 16 + coll] = o;
        }
    }
}

// ---------------------------------------------------------------- rms_norm(ctx)*rms_w * silu(gate) -> f16
__global__ void epilogue_k(const float* __restrict__ ctx, const float* __restrict__ gate_pre,
                           const float* __restrict__ rms_w, _Float16* __restrict__ y) {
    int gw = (blockIdx.x * blockDim.x + threadIdx.x) >> 6;
    int lane = threadIdx.x & 63;
    int s = gw >> 4, h = gw & 15;
    long base = (long)s * 2048 + h * 128;
    float2 cv = *(const float2*)&ctx[base + lane * 2];
    float ss = cv.x * cv.x + cv.y * cv.y;
#pragma unroll
    for (int m = 1; m < 64; m <<= 1) ss += __shfl_xor(ss, m);
    float sc = rsqrtf(ss * (1.f / 128.f) + 1e-6f);
    int d = lane * 2;
    float2 rw = *(const float2*)&rms_w[d];
    float g0 = silu_f(gate_pre[base + d]);
    float g1 = silu_f(gate_pre[base + d + 1]);
    f16x2 hv = { (_Float16)(cv.x * sc * rw.x * g0), (_Float16)(cv.y * sc * rw.y * g1) };
    *(f16x2*)&y[base + d] = hv;
}

// ---------------------------------------------------------------- launch
extern "C" void kernel_launch(void* const* d_in, const int* in_sizes, int n_in,
                              void* d_out, int out_size, void* d_ws, size_t ws_size,
                              hipStream_t stream) {
    const float* x       = (const float*)d_in[0];
    const float* w_qkv   = (const float*)d_in[1];
    const float* w_gate  = (const float*)d_in[2];
    const float* w_beta  = (const float*)d_in[3];
    const float* w_alpha = (const float*)d_in[4];
    const float* log_A   = (const float*)d_in[5];
    const float* dt_bias = (const float*)d_in[6];
    const float* conv_w  = (const float*)d_in[7];
    const float* rms_w   = (const float*)d_in[8];
    const float* w_out   = (const float*)d_in[9];
    float* outp = (float*)d_out;

    char* ws = (char*)d_ws;
    size_t off = 0;
    _Float16* xb     = (_Float16*)(ws + off); off += (size_t)1024 * 2048 * 2;
    _Float16* wqkvb  = (_Float16*)(ws + off); off += (size_t)4096 * 2048 * 2;
    _Float16* wgateb = (_Float16*)(ws + off); off += (size_t)2048 * 2048 * 2;
    _Float16* woutb  = (_Float16*)(ws + off); off += (size_t)2048 * 2048 * 2;
    _Float16* yb     = (_Float16*)(ws + off); off += (size_t)1024 * 2048 * 2;
    float* qkv_pre   = (float*)(ws + off);    off += (size_t)1024 * 4096 * 4;
    float* fqkv      = (float*)(ws + off);    off += (size_t)1024 * 4096 * 4;
    float* gate_pre  = (float*)(ws + off);    off += (size_t)1024 * 2048 * 4;
    float* ctx       = (float*)(ws + off);    off += (size_t)1024 * 16 * 128 * 4;
    float* betaB     = (float*)(ws + off);    off += (size_t)1024 * 16 * 4;
    float* alphaB    = (float*)(ws + off);    off += (size_t)1024 * 16 * 4;

    cvt_f16<<<2048, 256, 0, stream>>>(x, xb, 1024 * 2048);
    cvt_f16<<<8192, 256, 0, stream>>>(w_qkv, wqkvb, 4096 * 2048);
    cvt_f16<<<4096, 256, 0, stream>>>(w_gate, wgateb, 2048 * 2048);
    cvt_f16<<<4096, 256, 0, stream>>>(w_out, woutb, 2048 * 2048);

    gemm_bt<<<dim3(32, 8), 256, 0, stream>>>(xb, wqkvb, qkv_pre, 4096, 2048);
    gemm_bt<<<dim3(16, 8), 256, 0, stream>>>(xb, wgateb, gate_pre, 2048, 2048);
    proj_ba<<<1024, 256, 0, stream>>>(x, w_beta, w_alpha, log_A, dt_bias, betaB, alphaB);
    conv_silu<<<16384, 256, 0, stream>>>(qkv_pre, conv_w, fqkv);
    norm_qk<<<4096, 256, 0, stream>>>(fqkv);
    scan_kernel<<<128, 256, 0, stream>>>(fqkv, betaB, alphaB, ctx);
    epilogue_k<<<4096, 256, 0, stream>>>(ctx, gate_pre, rms_w, yb);
    gemm_bt<<<dim3(16, 8), 256, 0, stream>>>(yb, woutb, outp, 2048, 2048);
}

// Round 2
// 512.255 us; speedup vs baseline: 1.4359x; 1.4359x over previous
//
#include <hip/hip_runtime.h>

#define AS1 __attribute__((address_space(1)))
#define AS3 __attribute__((address_space(3)))

typedef _Float16 f16x8 __attribute__((ext_vector_type(8)));
typedef _Float16 f16x4 __attribute__((ext_vector_type(4)));
typedef _Float16 f16x2 __attribute__((ext_vector_type(2)));
typedef float f32x4 __attribute__((ext_vector_type(4)));

// ---------------------------------------------------------------- helpers
__device__ __forceinline__ float silu_f(float v) { return v / (1.f + expf(-v)); }

__device__ __forceinline__ void gload_lds16(const void* g, void* l) {
    __builtin_amdgcn_global_load_lds((AS1 void*)g, (AS3 void*)l, 16, 0, 0);
}

// DPP-based 16-lane row reduction: 4 VALU-speed adds, no DS pipe.
// Each level is an involutive pairing crossing halves: xor1, xor2,
// half-mirror (crosses quads), mirror (crosses octets).
template <int CTRL>
__device__ __forceinline__ float dpp_add(float v) {
    int s = __builtin_amdgcn_update_dpp(0, __float_as_int(v), CTRL, 0xF, 0xF, true);
    return v + __int_as_float(s);
}
__device__ __forceinline__ float row_reduce16(float v) {
    v = dpp_add<0xB1>(v);    // quad_perm [1,0,3,2]  (xor 1)
    v = dpp_add<0x4E>(v);    // quad_perm [2,3,0,1]  (xor 2)
    v = dpp_add<0x141>(v);   // row_half_mirror      (crosses quads)
    v = dpp_add<0x140>(v);   // row_mirror           (crosses octets)
    return v;
}

// ---------------------------------------------------------------- f32 -> f16 convert
__global__ void cvt_f16(const float* __restrict__ in, _Float16* __restrict__ out, int n) {
    int i = (blockIdx.x * blockDim.x + threadIdx.x) * 4;
    if (i >= n) return;
    float4 v = *(const float4*)&in[i];
    f16x4 h = { (_Float16)v.x, (_Float16)v.y, (_Float16)v.z, (_Float16)v.w };
    *(f16x4*)&out[i] = h;
}

// ---------------------------------------------------------------- GEMM: C = A * B^T
// A: (M x K) f16 row-major, B: (N x K) f16 row-major, C: (M x N) f32.
__global__ __launch_bounds__(256) void gemm_bt(const _Float16* __restrict__ A,
                                               const _Float16* __restrict__ B,
                                               float* __restrict__ C, int N, int K) {
    __shared__ _Float16 As[128 * 32];
    __shared__ _Float16 Bs[128 * 32];
    const int tid = threadIdx.x;
    const int rowA0 = blockIdx.y * 128, rowB0 = blockIdx.x * 128;
    const int lane = tid & 63;
    const int wave = tid >> 6;
    const int wr = (wave >> 1) * 64, wc = (wave & 1) * 64;
    const int fr = lane & 15, kof = (lane >> 4) * 8;
    const int sr0 = tid >> 2;
    const int sc0 = (tid & 3) * 8;

    f32x4 zero = {0.f, 0.f, 0.f, 0.f};
    f32x4 acc[4][4];
#pragma unroll
    for (int i = 0; i < 4; i++)
#pragma unroll
        for (int j = 0; j < 4; j++) acc[i][j] = zero;

    const _Float16* Abase = A + (long)(rowA0 + sr0) * K + sc0;
    const _Float16* Bbase = B + (long)(rowB0 + sr0) * K + sc0;
    const long chunk2 = (long)64 * K;

    for (int k0 = 0; k0 < K; k0 += 32) {
        __syncthreads();
        gload_lds16(Abase + k0,          &As[tid * 8]);
        gload_lds16(Abase + k0 + chunk2, &As[2048 + tid * 8]);
        gload_lds16(Bbase + k0,          &Bs[tid * 8]);
        gload_lds16(Bbase + k0 + chunk2, &Bs[2048 + tid * 8]);
        __syncthreads();
        f16x8 af[4], bf[4];
#pragma unroll
        for (int mi = 0; mi < 4; mi++) af[mi] = *(const f16x8*)&As[(wr + mi * 16 + fr) * 32 + kof];
#pragma unroll
        for (int ni = 0; ni < 4; ni++) bf[ni] = *(const f16x8*)&Bs[(wc + ni * 16 + fr) * 32 + kof];
#pragma unroll
        for (int mi = 0; mi < 4; mi++)
#pragma unroll
            for (int ni = 0; ni < 4; ni++)
                acc[mi][ni] = __builtin_amdgcn_mfma_f32_16x16x32_f16(af[mi], bf[ni], acc[mi][ni], 0, 0, 0);
    }
    const int rbase = (lane >> 4) * 4;
#pragma unroll
    for (int mi = 0; mi < 4; mi++)
#pragma unroll
        for (int ni = 0; ni < 4; ni++) {
            int row = rowA0 + wr + mi * 16 + rbase;
            int col = rowB0 + wc + ni * 16 + fr;
#pragma unroll
            for (int r = 0; r < 4; r++)
                C[(long)(row + r) * N + col] = acc[mi][ni][r];
        }
}

// ---------------------------------------------------------------- beta/alpha projections
__global__ __launch_bounds__(256) void proj_ba(const float* __restrict__ x,
                                               const float* __restrict__ w_beta,
                                               const float* __restrict__ w_alpha,
                                               const float* __restrict__ log_A,
                                               const float* __restrict__ dt_bias,
                                               float* __restrict__ betaB,
                                               float* __restrict__ alphaB) {
    __shared__ float xs[2048];
    const int s = blockIdx.x, tid = threadIdx.x;
    *(float4*)&xs[tid * 8]     = *(const float4*)&x[(long)s * 2048 + tid * 8];
    *(float4*)&xs[tid * 8 + 4] = *(const float4*)&x[(long)s * 2048 + tid * 8 + 4];
    __syncthreads();
    const int o = tid >> 3, j = tid & 7;
    const float* w = (o < 16) ? &w_beta[(long)o * 2048] : &w_alpha[(long)(o - 16) * 2048];
    float p = 0.f;
#pragma unroll 4
    for (int i = 0; i < 64; i++) {
        int d = i * 32 + j * 4;
        float4 wv = *(const float4*)&w[d];
        p += xs[d] * wv.x + xs[d + 1] * wv.y + xs[d + 2] * wv.z + xs[d + 3] * wv.w;
    }
    p += __shfl_xor(p, 1); p += __shfl_xor(p, 2); p += __shfl_xor(p, 4);
    if (j == 0) {
        if (o < 16) {
            betaB[s * 16 + o] = 1.f / (1.f + expf(-p));
        } else {
            int h = o - 16;
            float t = p + dt_bias[h];
            float sp = (t > 20.f) ? t : log1pf(expf(t));
            alphaB[s * 16 + h] = expf(-expf(log_A[h]) * sp);
        }
    }
}

// ---------------------------------------------------------------- causal depthwise conv(K=4) + SiLU
// pre has row stride 6144 (fused qkv+gate gemm output); fqkv out stride 4096.
__global__ void conv_silu(const float* __restrict__ pre, const float* __restrict__ cw,
                          float* __restrict__ outp) {
    int i = blockIdx.x * blockDim.x + threadIdx.x;  // 1024*4096
    int s = i >> 12, c = i & 4095;
    float4 w = *(const float4*)&cw[c * 4];
    float acc = pre[(long)s * 6144 + c] * w.w;
    if (s >= 1) acc += pre[(long)(s - 1) * 6144 + c] * w.z;
    if (s >= 2) acc += pre[(long)(s - 2) * 6144 + c] * w.y;
    if (s >= 3) acc += pre[(long)(s - 3) * 6144 + c] * w.x;
    outp[i] = silu_f(acc);
}

// ---------------------------------------------------------------- in-place l2 norm of q,k
__global__ void norm_qk(float* __restrict__ fqkv) {
    int gw = (blockIdx.x * blockDim.x + threadIdx.x) >> 6;
    int lane = threadIdx.x & 63;
    int s = gw >> 4, idx = gw & 15;
    float* base = fqkv + (long)s * 4096 + (idx < 8 ? idx * 128 : 1024 + (idx - 8) * 128);
    float2 v = *(float2*)&base[lane * 2];
    float ss = v.x * v.x + v.y * v.y;
#pragma unroll
    for (int m = 1; m < 64; m <<= 1) ss += __shfl_xor(ss, m);
    float sc = rsqrtf(ss + 1e-6f);
    if (idx < 8) sc *= 0.08838834764831843f;  // 1/sqrt(128), queries only
    v.x *= sc; v.y *= sc;
    *(float2*)&base[lane * 2] = v;
}

// ---------------------------------------------------------------- gated delta rule scan
// Column-parallel: 16 cols/block x 16 lanes/col; DPP row reductions keep the
// serial chain on the VALU pipe (no DS-latency shuffles).
// o_t = a*(q^T S_{t-1}) + (q.k)*u_t with q.k precomputed per chunk.
#define SCT 32
__global__ __launch_bounds__(256) void scan_kernel(const float* __restrict__ fqkv,
                                                   const float* __restrict__ betaB,
                                                   const float* __restrict__ alphaB,
                                                   float* __restrict__ ctx) {
    __shared__ float lk[SCT][128];
    __shared__ float lq[SCT][128];
    __shared__ float lv[SCT][16];
    __shared__ float la[SCT];
    __shared__ float lb[SCT];
    __shared__ float lqk[SCT];
    const int tid = threadIdx.x;
    const int h = blockIdx.x >> 3;
    const int vblk = blockIdx.x & 7;
    const int hq = h >> 1;                 // rep=2 head mapping
    const int coll = tid >> 4;             // column within block (0..15)
    const int kg = tid & 15;               // k-group within column (DPP row lane)
    const int kb = kg * 8;
    const float* qbase = fqkv + hq * 128;
    const float* kbase = fqkv + 1024 + hq * 128;
    const float* vbase = fqkv + 2048 + h * 128 + vblk * 16;
    float S[8];
#pragma unroll
    for (int j = 0; j < 8; j++) S[j] = 0.f;

    for (int s0 = 0; s0 < 1024; s0 += SCT) {
        __syncthreads();
#pragma unroll
        for (int r = 0; r < 16; r++) {
            int e = r * 256 + tid;
            int t = e >> 7, d = e & 127;
            lk[t][d] = kbase[(long)(s0 + t) * 4096 + d];
            lq[t][d] = qbase[(long)(s0 + t) * 4096 + d];
        }
        {
            int t = tid >> 4, vv = tid & 15;
            lv[t][vv] = vbase[(long)(s0 + t) * 4096 + vv];
            int e = tid + 256; int t2 = e >> 4; int vv2 = e & 15;
            lv[t2][vv2] = vbase[(long)(s0 + t2) * 4096 + vv2];
        }
        if (tid < SCT) {
            la[tid] = alphaB[(s0 + tid) * 16 + h];
            lb[tid] = betaB[(s0 + tid) * 16 + h];
        }
        __syncthreads();
        // precompute qk_t = q_t . k_t for the chunk (off the serial chain)
#pragma unroll
        for (int rep = 0; rep < 2; rep++) {
            int t = coll + rep * 16;
            float a0[8], b0[8];
            *(float4*)&a0[0] = *(const float4*)&lq[t][kb];
            *(float4*)&a0[4] = *(const float4*)&lq[t][kb + 4];
            *(float4*)&b0[0] = *(const float4*)&lk[t][kb];
            *(float4*)&b0[4] = *(const float4*)&lk[t][kb + 4];
            float p = 0.f;
#pragma unroll
            for (int j = 0; j < 8; j++) p += a0[j] * b0[j];
            p = row_reduce16(p);
            if (kg == 0) lqk[t] = p;
        }
        __syncthreads();
        for (int t = 0; t < SCT; t++) {
            float at = la[t], bt = lb[t], qkt = lqk[t];
            float kk[8], qq[8];
            *(float4*)&kk[0] = *(const float4*)&lk[t][kb];
            *(float4*)&kk[4] = *(const float4*)&lk[t][kb + 4];
            *(float4*)&qq[0] = *(const float4*)&lq[t][kb];
            *(float4*)&qq[4] = *(const float4*)&lq[t][kb + 4];
            float pk0 = 0.f, pk1 = 0.f, pq0 = 0.f, pq1 = 0.f;
#pragma unroll
            for (int j = 0; j < 4; j++) {
                pk0 = fmaf(kk[j], S[j], pk0);
                pk1 = fmaf(kk[j + 4], S[j + 4], pk1);
                pq0 = fmaf(qq[j], S[j], pq0);
                pq1 = fmaf(qq[j + 4], S[j + 4], pq1);
            }
            float pk = pk0 + pk1, pq = pq0 + pq1;
            // interleaved DPP butterflies (VALU pipe, both chains in flight)
            pk = dpp_add<0xB1>(pk);  pq = dpp_add<0xB1>(pq);
            pk = dpp_add<0x4E>(pk);  pq = dpp_add<0x4E>(pq);
            pk = dpp_add<0x141>(pk); pq = dpp_add<0x141>(pq);
            pk = dpp_add<0x140>(pk); pq = dpp_add<0x140>(pq);
            float u = bt * (lv[t][coll] - at * pk);
#pragma unroll
            for (int j = 0; j < 8; j++) S[j] = fmaf(at, S[j], kk[j] * u);
            if (kg == 0)
                ctx[(long)(s0 + t) * 2048 + h * 128 + vblk * 16 + coll] = fmaf(at, pq, qkt * u);
        }
    }
}

// ---------------------------------------------------------------- rms_norm(ctx)*rms_w * silu(gate) -> f16
// gate lives in pre[] at column offset 4096, row stride 6144.
__global__ void epilogue_k(const float* __restrict__ ctx, const float* __restrict__ pre,
                           const float* __restrict__ rms_w, _Float16* __restrict__ y) {
    int gw = (blockIdx.x * blockDim.x + threadIdx.x) >> 6;
    int lane = threadIdx.x & 63;
    int s = gw >> 4, h = gw & 15;
    long base = (long)s * 2048 + h * 128;
    long gbase = (long)s * 6144 + 4096 + h * 128;
    float2 cv = *(const float2*)&ctx[base + lane * 2];
    float ss = cv.x * cv.x + cv.y * cv.y;
#pragma unroll
    for (int m = 1; m < 64; m <<= 1) ss += __shfl_xor(ss, m);
    float sc = rsqrtf(ss * (1.f / 128.f) + 1e-6f);
    int d = lane * 2;
    float2 rw = *(const float2*)&rms_w[d];
    float g0 = silu_f(pre[gbase + d]);
    float g1 = silu_f(pre[gbase + d + 1]);
    f16x2 hv = { (_Float16)(cv.x * sc * rw.x * g0), (_Float16)(cv.y * sc * rw.y * g1) };
    *(f16x2*)&y[base + d] = hv;
}

// ---------------------------------------------------------------- launch
extern "C" void kernel_launch(void* const* d_in, const int* in_sizes, int n_in,
                              void* d_out, int out_size, void* d_ws, size_t ws_size,
                              hipStream_t stream) {
    const float* x       = (const float*)d_in[0];
    const float* w_qkv   = (const float*)d_in[1];
    const float* w_gate  = (const float*)d_in[2];
    const float* w_beta  = (const float*)d_in[3];
    const float* w_alpha = (const float*)d_in[4];
    const float* log_A   = (const float*)d_in[5];
    const float* dt_bias = (const float*)d_in[6];
    const float* conv_w  = (const float*)d_in[7];
    const float* rms_w   = (const float*)d_in[8];
    const float* w_out   = (const float*)d_in[9];
    float* outp = (float*)d_out;

    char* ws = (char*)d_ws;
    size_t off = 0;
    _Float16* xb     = (_Float16*)(ws + off); off += (size_t)1024 * 2048 * 2;
    _Float16* wfused = (_Float16*)(ws + off); off += (size_t)6144 * 2048 * 2;  // qkv rows 0..4095, gate 4096..6143
    _Float16* woutb  = (_Float16*)(ws + off); off += (size_t)2048 * 2048 * 2;
    _Float16* yb     = (_Float16*)(ws + off); off += (size_t)1024 * 2048 * 2;
    float* pre       = (float*)(ws + off);    off += (size_t)1024 * 6144 * 4;  // cols 0..4095 qkv, 4096..6143 gate
    float* fqkv      = (float*)(ws + off);    off += (size_t)1024 * 4096 * 4;
    float* ctx       = (float*)(ws + off);    off += (size_t)1024 * 16 * 128 * 4;
    float* betaB     = (float*)(ws + off);    off += (size_t)1024 * 16 * 4;
    float* alphaB    = (float*)(ws + off);    off += (size_t)1024 * 16 * 4;

    cvt_f16<<<2048, 256, 0, stream>>>(x, xb, 1024 * 2048);
    cvt_f16<<<8192, 256, 0, stream>>>(w_qkv, wfused, 4096 * 2048);
    cvt_f16<<<4096, 256, 0, stream>>>(w_gate, wfused + (size_t)4096 * 2048, 2048 * 2048);
    cvt_f16<<<4096, 256, 0, stream>>>(w_out, woutb, 2048 * 2048);

    gemm_bt<<<dim3(48, 8), 256, 0, stream>>>(xb, wfused, pre, 6144, 2048);
    proj_ba<<<1024, 256, 0, stream>>>(x, w_beta, w_alpha, log_A, dt_bias, betaB, alphaB);
    conv_silu<<<16384, 256, 0, stream>>>(pre, conv_w, fqkv);
    norm_qk<<<4096, 256, 0, stream>>>(fqkv);
    scan_kernel<<<128, 256, 0, stream>>>(fqkv, betaB, alphaB, ctx);
    epilogue_k<<<4096, 256, 0, stream>>>(ctx, pre, rms_w, yb);
    gemm_bt<<<dim3(16, 8), 256, 0, stream>>>(yb, woutb, outp, 2048, 2048);
}

// Round 3
// 417.625 us; speedup vs baseline: 1.7613x; 1.2266x over previous
//
#include <hip/hip_runtime.h>

#define AS1 __attribute__((address_space(1)))
#define AS3 __attribute__((address_space(3)))

typedef _Float16 f16x8 __attribute__((ext_vector_type(8)));
typedef _Float16 f16x4 __attribute__((ext_vector_type(4)));
typedef _Float16 f16x2 __attribute__((ext_vector_type(2)));
typedef float f32x4 __attribute__((ext_vector_type(4)));

#define MFMA16(a, b, c) __builtin_amdgcn_mfma_f32_16x16x32_f16((a), (b), (c), 0, 0, 0)

// ---------------------------------------------------------------- helpers
__device__ __forceinline__ float silu_f(float v) { return v / (1.f + expf(-v)); }

__device__ __forceinline__ void gload_lds16(const void* g, void* l) {
    __builtin_amdgcn_global_load_lds((AS1 void*)g, (AS3 void*)l, 16, 0, 0);
}

// ---------------------------------------------------------------- f32 -> f16 convert
__global__ void cvt_f16(const float* __restrict__ in, _Float16* __restrict__ out, int n) {
    int i = (blockIdx.x * blockDim.x + threadIdx.x) * 4;
    if (i >= n) return;
    float4 v = *(const float4*)&in[i];
    f16x4 h = { (_Float16)v.x, (_Float16)v.y, (_Float16)v.z, (_Float16)v.w };
    *(f16x4*)&out[i] = h;
}

// ---------------------------------------------------------------- GEMM: C = A * B^T
__global__ __launch_bounds__(256) void gemm_bt(const _Float16* __restrict__ A,
                                               const _Float16* __restrict__ B,
                                               float* __restrict__ C, int N, int K) {
    __shared__ _Float16 As[128 * 32];
    __shared__ _Float16 Bs[128 * 32];
    const int tid = threadIdx.x;
    const int rowA0 = blockIdx.y * 128, rowB0 = blockIdx.x * 128;
    const int lane = tid & 63;
    const int wave = tid >> 6;
    const int wr = (wave >> 1) * 64, wc = (wave & 1) * 64;
    const int fr = lane & 15, kof = (lane >> 4) * 8;
    const int sr0 = tid >> 2;
    const int sc0 = (tid & 3) * 8;

    f32x4 zero = {0.f, 0.f, 0.f, 0.f};
    f32x4 acc[4][4];
#pragma unroll
    for (int i = 0; i < 4; i++)
#pragma unroll
        for (int j = 0; j < 4; j++) acc[i][j] = zero;

    const _Float16* Abase = A + (long)(rowA0 + sr0) * K + sc0;
    const _Float16* Bbase = B + (long)(rowB0 + sr0) * K + sc0;
    const long chunk2 = (long)64 * K;

    for (int k0 = 0; k0 < K; k0 += 32) {
        __syncthreads();
        gload_lds16(Abase + k0,          &As[tid * 8]);
        gload_lds16(Abase + k0 + chunk2, &As[2048 + tid * 8]);
        gload_lds16(Bbase + k0,          &Bs[tid * 8]);
        gload_lds16(Bbase + k0 + chunk2, &Bs[2048 + tid * 8]);
        __syncthreads();
        f16x8 af[4], bf[4];
#pragma unroll
        for (int mi = 0; mi < 4; mi++) af[mi] = *(const f16x8*)&As[(wr + mi * 16 + fr) * 32 + kof];
#pragma unroll
        for (int ni = 0; ni < 4; ni++) bf[ni] = *(const f16x8*)&Bs[(wc + ni * 16 + fr) * 32 + kof];
#pragma unroll
        for (int mi = 0; mi < 4; mi++)
#pragma unroll
            for (int ni = 0; ni < 4; ni++)
                acc[mi][ni] = MFMA16(af[mi], bf[ni], acc[mi][ni]);
    }
    const int rbase = (lane >> 4) * 4;
#pragma unroll
    for (int mi = 0; mi < 4; mi++)
#pragma unroll
        for (int ni = 0; ni < 4; ni++) {
            int row = rowA0 + wr + mi * 16 + rbase;
            int col = rowB0 + wc + ni * 16 + fr;
#pragma unroll
            for (int r = 0; r < 4; r++)
                C[(long)(row + r) * N + col] = acc[mi][ni][r];
        }
}

// ---------------------------------------------------------------- beta / log-alpha projections
__global__ __launch_bounds__(256) void proj_ba(const float* __restrict__ x,
                                               const float* __restrict__ w_beta,
                                               const float* __restrict__ w_alpha,
                                               const float* __restrict__ log_A,
                                               const float* __restrict__ dt_bias,
                                               float* __restrict__ betaB,
                                               float* __restrict__ lalphaB) {
    __shared__ float xs[2048];
    const int s = blockIdx.x, tid = threadIdx.x;
    *(float4*)&xs[tid * 8]     = *(const float4*)&x[(long)s * 2048 + tid * 8];
    *(float4*)&xs[tid * 8 + 4] = *(const float4*)&x[(long)s * 2048 + tid * 8 + 4];
    __syncthreads();
    const int o = tid >> 3, j = tid & 7;
    const float* w = (o < 16) ? &w_beta[(long)o * 2048] : &w_alpha[(long)(o - 16) * 2048];
    float p = 0.f;
#pragma unroll 4
    for (int i = 0; i < 64; i++) {
        int d = i * 32 + j * 4;
        float4 wv = *(const float4*)&w[d];
        p += xs[d] * wv.x + xs[d + 1] * wv.y + xs[d + 2] * wv.z + xs[d + 3] * wv.w;
    }
    p += __shfl_xor(p, 1); p += __shfl_xor(p, 2); p += __shfl_xor(p, 4);
    if (j == 0) {
        if (o < 16) {
            betaB[s * 16 + o] = 1.f / (1.f + expf(-p));
        } else {
            int h = o - 16;
            float t = p + dt_bias[h];
            float sp = (t > 20.f) ? t : log1pf(expf(t));
            lalphaB[s * 16 + h] = -expf(log_A[h]) * sp;   // log(alpha), exact in log-domain
        }
    }
}

// ---------------------------------------------------------------- causal depthwise conv(K=4) + SiLU
__global__ void conv_silu(const float* __restrict__ pre, const float* __restrict__ cw,
                          float* __restrict__ outp) {
    int i = blockIdx.x * blockDim.x + threadIdx.x;  // 1024*4096
    int s = i >> 12, c = i & 4095;
    float4 w = *(const float4*)&cw[c * 4];
    float acc = pre[(long)s * 6144 + c] * w.w;
    if (s >= 1) acc += pre[(long)(s - 1) * 6144 + c] * w.z;
    if (s >= 2) acc += pre[(long)(s - 2) * 6144 + c] * w.y;
    if (s >= 3) acc += pre[(long)(s - 3) * 6144 + c] * w.x;
    outp[i] = silu_f(acc);
}

// ---------------------------------------------------------------- in-place l2 norm of q,k
__global__ void norm_qk(float* __restrict__ fqkv) {
    int gw = (blockIdx.x * blockDim.x + threadIdx.x) >> 6;
    int lane = threadIdx.x & 63;
    int s = gw >> 4, idx = gw & 15;
    float* base = fqkv + (long)s * 4096 + (idx < 8 ? idx * 128 : 1024 + (idx - 8) * 128);
    float2 v = *(float2*)&base[lane * 2];
    float ss = v.x * v.x + v.y * v.y;
#pragma unroll
    for (int m = 1; m < 64; m <<= 1) ss += __shfl_xor(ss, m);
    float sc = rsqrtf(ss + 1e-6f);
    if (idx < 8) sc *= 0.08838834764831843f;  // 1/sqrt(128), queries only
    v.x *= sc; v.y *= sc;
    *(float2*)&base[lane * 2] = v;
}

// ---------------------------------------------------------------- chunked delta rule: precompute
// Per (head, chunk): gamma cumsum; T = tril_strict(diag(beta) Gam K K^T);
// M = tril(Gam Q K^T); Qt~ = diag(gamma) Q; Kt~^T = scaled K^T. All f16 out.
__global__ __launch_bounds__(256) void prep_chunk(const float* __restrict__ fqkv,
                                                  const float* __restrict__ betaB,
                                                  const float* __restrict__ lalphaB,
                                                  _Float16* __restrict__ Tw,
                                                  _Float16* __restrict__ Mw,
                                                  _Float16* __restrict__ QTw,
                                                  _Float16* __restrict__ KTw,
                                                  float* __restrict__ bgam,
                                                  float* __restrict__ gamC) {
    __shared__ _Float16 Kh[64 * 128];
    __shared__ _Float16 Qh[64 * 128];
    __shared__ float lg[64], bet[64];
    const int hc = blockIdx.x;
    const int h = hc >> 4, c = hc & 15, hq = h >> 1, s0 = c * 64;
    const int tid = threadIdx.x;
    if (tid < 64) {
        float la = lalphaB[(s0 + tid) * 16 + h];
#pragma unroll
        for (int d = 1; d < 64; d <<= 1) {
            float t = __shfl_up(la, d, 64);
            if (tid >= d) la += t;
        }
        lg[tid] = la;
        bet[tid] = betaB[(s0 + tid) * 16 + h];
    }
    for (int e = tid; e < 8192; e += 256) {
        int t = e >> 7, m = e & 127;
        Kh[e] = (_Float16)fqkv[(long)(s0 + t) * 4096 + 1024 + hq * 128 + m];
        Qh[e] = (_Float16)fqkv[(long)(s0 + t) * 4096 + hq * 128 + m];
    }
    __syncthreads();
    if (tid < 64) bgam[hc * 64 + tid] = bet[tid] * expf(lg[tid]);
    if (tid == 0) gamC[hc] = expf(lg[63]);
    for (int e = tid; e < 8192; e += 256) {
        int t = e >> 7;
        QTw[(long)hc * 8192 + e] = (_Float16)(expf(lg[t]) * (float)Qh[e]);
    }
    for (int e = tid; e < 8192; e += 256) {
        int m = e >> 6, t = e & 63;
        KTw[(long)hc * 8192 + e] = (_Float16)(expf(lg[63] - lg[t]) * (float)Kh[t * 128 + m]);
    }
    // KK^T and QK^T MFMAs: wave w owns out rows 16w..16w+15
    const int wv = tid >> 6, lane = tid & 63, fr = lane & 15, kof = (lane >> 4) * 8, quad = lane >> 4;
    f32x4 accT[4], accM[4];
    f32x4 zero = {0.f, 0.f, 0.f, 0.f};
#pragma unroll
    for (int ci = 0; ci < 4; ci++) { accT[ci] = zero; accM[ci] = zero; }
    for (int k0 = 0; k0 < 128; k0 += 32) {
        f16x8 ak = *(const f16x8*)&Kh[(wv * 16 + fr) * 128 + k0 + kof];
        f16x8 aq = *(const f16x8*)&Qh[(wv * 16 + fr) * 128 + k0 + kof];
#pragma unroll
        for (int ci = 0; ci < 4; ci++) {
            f16x8 bk = *(const f16x8*)&Kh[(ci * 16 + fr) * 128 + k0 + kof];
            accT[ci] = MFMA16(ak, bk, accT[ci]);
            accM[ci] = MFMA16(aq, bk, accM[ci]);
        }
    }
#pragma unroll
    for (int ci = 0; ci < 4; ci++)
#pragma unroll
        for (int r = 0; r < 4; r++) {
            int t = wv * 16 + quad * 4 + r, i = ci * 16 + fr;
            float e = expf(lg[t] - lg[i]);
            Tw[(long)hc * 4096 + t * 64 + i] = (_Float16)((i < t) ? bet[t] * e * accT[ci][r] : 0.f);
            Mw[(long)hc * 4096 + t * 64 + i] = (_Float16)((i <= t) ? e * accM[ci][r] : 0.f);
        }
}

// ---------------------------------------------------------------- blocked forward substitution
// Solves (I+T) X = RHS per (head,chunk,half). half0: RHS = diag(beta)V -> WT out (transposed);
// half1: RHS = diag(beta*gamma)K -> B out (row-major). Per-thread column, LDS-backed.
__global__ __launch_bounds__(128) void solve_chunk(const float* __restrict__ fqkv,
                                                   const float* __restrict__ betaB,
                                                   const float* __restrict__ bgam,
                                                   const _Float16* __restrict__ Tw,
                                                   _Float16* __restrict__ WTw,
                                                   _Float16* __restrict__ Bw) {
    __shared__ float Tl[64 * 64];   // 16 KB
    __shared__ float XD[64 * 128];  // 32 KB
    const int bid = blockIdx.x;
    const int hc = bid >> 1, half = bid & 1;
    const int h = hc >> 4, c = hc & 15, hq = h >> 1, s0 = c * 64;
    const int j = threadIdx.x;
    for (int e = j; e < 4096; e += 128) Tl[e] = (float)Tw[(long)hc * 4096 + e];
    __syncthreads();
    float Xa[16];
    for (int a = 0; a < 4; ++a) {
#pragma unroll
        for (int r = 0; r < 16; ++r) {
            int t = a * 16 + r;
            float rv;
            if (half == 0)
                rv = betaB[(s0 + t) * 16 + h] * fqkv[(long)(s0 + t) * 4096 + 2048 + h * 128 + j];
            else
                rv = bgam[hc * 64 + t] * fqkv[(long)(s0 + t) * 4096 + 1024 + hq * 128 + j];
            Xa[r] = rv;
        }
        for (int b = 0; b < a; ++b)
            for (int k = 0; k < 16; ++k) {
                float xk = XD[(b * 16 + k) * 128 + j];
#pragma unroll
                for (int r = 0; r < 16; ++r)
                    Xa[r] -= Tl[(a * 16 + r) * 64 + b * 16 + k] * xk;
            }
#pragma unroll
        for (int tp = 0; tp < 16; ++tp) {
            float xt = Xa[tp];
#pragma unroll
            for (int sp = 0; sp < 16; ++sp)
                if (sp > tp) Xa[sp] -= Tl[(a * 16 + sp) * 64 + a * 16 + tp] * xt;
        }
#pragma unroll
        for (int r = 0; r < 16; ++r) XD[(a * 16 + r) * 128 + j] = Xa[r];
    }
    __syncthreads();
    if (half == 0) {
        for (int t = 0; t < 64; ++t)
            WTw[((long)hc * 128 + j) * 64 + t] = (_Float16)XD[t * 128 + j];
    } else {
        for (int t = 0; t < 64; ++t)
            Bw[((long)hc * 64 + t) * 128 + j] = (_Float16)XD[t * 128 + j];
    }
}

// ---------------------------------------------------------------- serial chunk scan (MFMA)
// Grid 64 = (head, dv-slice of 32). State S^T kept in LDS as f16 hi+lo split.
// Per chunk: UT = WT - S^T B^T ; O^T = S^T Qt~^T + UT M^T ; S'^T = gC S^T + UT Kt~.
__global__ __launch_bounds__(256) void chunk_scan(const _Float16* __restrict__ Bw,
                                                  const _Float16* __restrict__ WTw,
                                                  const _Float16* __restrict__ KTw,
                                                  const _Float16* __restrict__ QTw,
                                                  const _Float16* __restrict__ Mw,
                                                  const float* __restrict__ gamC,
                                                  float* __restrict__ ctx) {
    __shared__ _Float16 ST16[32 * 128], STlo[32 * 128];  // 8 + 8 KB
    __shared__ _Float16 UT16[32 * 64], UTlo[32 * 64];    // 4 + 4 KB
    const int h = blockIdx.x >> 2, q4 = blockIdx.x & 3;
    const int tid = threadIdx.x, wv = tid >> 6, lane = tid & 63;
    const int fr = lane & 15, kof = (lane >> 4) * 8, quad = lane >> 4;
    const int jr = wv & 1, wh = wv >> 1;
    f32x4 zero = {0.f, 0.f, 0.f, 0.f};
    for (int e = tid; e < 4096; e += 256) { ST16[e] = (_Float16)0.f; STlo[e] = (_Float16)0.f; }
    __syncthreads();
    for (int c = 0; c < 16; ++c) {
        const long hc = h * 16 + c;
        const float gC = gamC[hc];
        const _Float16* Bp  = Bw  + hc * 8192;
        const _Float16* WTp = WTw + hc * 8192;
        const _Float16* KTp = KTw + hc * 8192;
        const _Float16* QTp = QTw + hc * 8192;
        const _Float16* Mp  = Mw  + hc * 4096;
        // ---- stage 1: UT[j][t] = WT[j][t] - sum_m ST[j][m] * B[t][m]
        f32x4 a1[2] = {zero, zero};
        for (int k0 = 0; k0 < 128; k0 += 32) {
            f16x8 s16 = *(const f16x8*)&ST16[(jr * 16 + fr) * 128 + k0 + kof];
            f16x8 slo = *(const f16x8*)&STlo[(jr * 16 + fr) * 128 + k0 + kof];
#pragma unroll
            for (int u = 0; u < 2; ++u) {
                int t0 = (wh * 2 + u) * 16;
                f16x8 bf = *(const f16x8*)&Bp[(t0 + fr) * 128 + k0 + kof];
                a1[u] = MFMA16(s16, bf, a1[u]);
                a1[u] = MFMA16(slo, bf, a1[u]);
            }
        }
#pragma unroll
        for (int u = 0; u < 2; ++u) {
            int t0 = (wh * 2 + u) * 16;
#pragma unroll
            for (int r = 0; r < 4; ++r) {
                int jl = jr * 16 + quad * 4 + r, tl = t0 + fr;
                float w = (float)WTp[(long)(q4 * 32 + jl) * 64 + tl];
                float uu = w - a1[u][r];
                _Float16 u16 = (_Float16)uu;
                UT16[jl * 64 + tl] = u16;
                UTlo[jl * 64 + tl] = (_Float16)(uu - (float)u16);
            }
        }
        __syncthreads();
        // ---- stage 2a: state acc over m-half wh*64 (4 tiles)
        f32x4 as[4] = {zero, zero, zero, zero};
        for (int k0 = 0; k0 < 64; k0 += 32) {
            f16x8 u16 = *(const f16x8*)&UT16[(jr * 16 + fr) * 64 + k0 + kof];
            f16x8 ulo = *(const f16x8*)&UTlo[(jr * 16 + fr) * 64 + k0 + kof];
#pragma unroll
            for (int mt = 0; mt < 4; ++mt) {
                int m0 = wh * 64 + mt * 16;
                f16x8 kf = *(const f16x8*)&KTp[(m0 + fr) * 64 + k0 + kof];
                as[mt] = MFMA16(u16, kf, as[mt]);
                as[mt] = MFMA16(ulo, kf, as[mt]);
            }
        }
        // ---- stage 2b: output acc O^T[j][t] (2 tiles)
        f32x4 ao[2] = {zero, zero};
        for (int k0 = 0; k0 < 128; k0 += 32) {
            f16x8 s16 = *(const f16x8*)&ST16[(jr * 16 + fr) * 128 + k0 + kof];
            f16x8 slo = *(const f16x8*)&STlo[(jr * 16 + fr) * 128 + k0 + kof];
#pragma unroll
            for (int u = 0; u < 2; ++u) {
                int t0 = (wh * 2 + u) * 16;
                f16x8 qf = *(const f16x8*)&QTp[(t0 + fr) * 128 + k0 + kof];
                ao[u] = MFMA16(s16, qf, ao[u]);
                ao[u] = MFMA16(slo, qf, ao[u]);
            }
        }
        for (int k0 = 0; k0 < 64; k0 += 32) {
            f16x8 u16 = *(const f16x8*)&UT16[(jr * 16 + fr) * 64 + k0 + kof];
#pragma unroll
            for (int u = 0; u < 2; ++u) {
                int t0 = (wh * 2 + u) * 16;
                f16x8 mf = *(const f16x8*)&Mp[(t0 + fr) * 64 + k0 + kof];
                ao[u] = MFMA16(u16, mf, ao[u]);
            }
        }
        __syncthreads();  // all reads of old ST complete
        // ---- write new state (own positions only)
#pragma unroll
        for (int mt = 0; mt < 4; ++mt)
#pragma unroll
            for (int r = 0; r < 4; ++r) {
                int jl = jr * 16 + quad * 4 + r, ml = wh * 64 + mt * 16 + fr;
                float old = (float)ST16[jl * 128 + ml] + (float)STlo[jl * 128 + ml];
                float sv = gC * old + as[mt][r];
                _Float16 s16v = (_Float16)sv;
                ST16[jl * 128 + ml] = s16v;
                STlo[jl * 128 + ml] = (_Float16)(sv - (float)s16v);
            }
        // ---- write O to ctx
        int s0 = c * 64;
#pragma unroll
        for (int u = 0; u < 2; ++u)
#pragma unroll
            for (int r = 0; r < 4; ++r) {
                int jl = jr * 16 + quad * 4 + r, tl = (wh * 2 + u) * 16 + fr;
                ctx[(long)(s0 + tl) * 2048 + h * 128 + q4 * 32 + jl] = ao[u][r];
            }
        __syncthreads();
    }
}

// ---------------------------------------------------------------- rms_norm(ctx)*rms_w * silu(gate) -> f16
__global__ void epilogue_k(const float* __restrict__ ctx, const float* __restrict__ pre,
                           const float* __restrict__ rms_w, _Float16* __restrict__ y) {
    int gw = (blockIdx.x * blockDim.x + threadIdx.x) >> 6;
    int lane = threadIdx.x & 63;
    int s = gw >> 4, h = gw & 15;
    long base = (long)s * 2048 + h * 128;
    long gbase = (long)s * 6144 + 4096 + h * 128;
    float2 cv = *(const float2*)&ctx[base + lane * 2];
    float ss = cv.x * cv.x + cv.y * cv.y;
#pragma unroll
    for (int m = 1; m < 64; m <<= 1) ss += __shfl_xor(ss, m);
    float sc = rsqrtf(ss * (1.f / 128.f) + 1e-6f);
    int d = lane * 2;
    float2 rw = *(const float2*)&rms_w[d];
    float g0 = silu_f(pre[gbase + d]);
    float g1 = silu_f(pre[gbase + d + 1]);
    f16x2 hv = { (_Float16)(cv.x * sc * rw.x * g0), (_Float16)(cv.y * sc * rw.y * g1) };
    *(f16x2*)&y[base + d] = hv;
}

// ---------------------------------------------------------------- launch
extern "C" void kernel_launch(void* const* d_in, const int* in_sizes, int n_in,
                              void* d_out, int out_size, void* d_ws, size_t ws_size,
                              hipStream_t stream) {
    const float* x       = (const float*)d_in[0];
    const float* w_qkv   = (const float*)d_in[1];
    const float* w_gate  = (const float*)d_in[2];
    const float* w_beta  = (const float*)d_in[3];
    const float* w_alpha = (const float*)d_in[4];
    const float* log_A   = (const float*)d_in[5];
    const float* dt_bias = (const float*)d_in[6];
    const float* conv_w  = (const float*)d_in[7];
    const float* rms_w   = (const float*)d_in[8];
    const float* w_out   = (const float*)d_in[9];
    float* outp = (float*)d_out;

    char* ws = (char*)d_ws;
    size_t off = 0;
    _Float16* xb     = (_Float16*)(ws + off); off += (size_t)1024 * 2048 * 2;
    _Float16* wfused = (_Float16*)(ws + off); off += (size_t)6144 * 2048 * 2;
    _Float16* woutb  = (_Float16*)(ws + off); off += (size_t)2048 * 2048 * 2;
    _Float16* yb     = (_Float16*)(ws + off); off += (size_t)1024 * 2048 * 2;
    float* pre       = (float*)(ws + off);    off += (size_t)1024 * 6144 * 4;
    float* fqkv      = (float*)(ws + off);    off += (size_t)1024 * 4096 * 4;
    float* ctx       = (float*)(ws + off);    off += (size_t)1024 * 16 * 128 * 4;
    float* betaB     = (float*)(ws + off);    off += (size_t)1024 * 16 * 4;
    float* lalphaB   = (float*)(ws + off);    off += (size_t)1024 * 16 * 4;
    _Float16* Tw     = (_Float16*)(ws + off); off += (size_t)256 * 4096 * 2;
    _Float16* Mw     = (_Float16*)(ws + off); off += (size_t)256 * 4096 * 2;
    _Float16* QTw    = (_Float16*)(ws + off); off += (size_t)256 * 8192 * 2;
    _Float16* KTw    = (_Float16*)(ws + off); off += (size_t)256 * 8192 * 2;
    _Float16* WTw    = (_Float16*)(ws + off); off += (size_t)256 * 8192 * 2;
    _Float16* Bw     = (_Float16*)(ws + off); off += (size_t)256 * 8192 * 2;
    float* bgam      = (float*)(ws + off);    off += (size_t)256 * 64 * 4;
    float* gamC      = (float*)(ws + off);    off += (size_t)256 * 4;

    cvt_f16<<<2048, 256, 0, stream>>>(x, xb, 1024 * 2048);
    cvt_f16<<<8192, 256, 0, stream>>>(w_qkv, wfused, 4096 * 2048);
    cvt_f16<<<4096, 256, 0, stream>>>(w_gate, wfused + (size_t)4096 * 2048, 2048 * 2048);
    cvt_f16<<<4096, 256, 0, stream>>>(w_out, woutb, 2048 * 2048);

    gemm_bt<<<dim3(48, 8), 256, 0, stream>>>(xb, wfused, pre, 6144, 2048);
    proj_ba<<<1024, 256, 0, stream>>>(x, w_beta, w_alpha, log_A, dt_bias, betaB, lalphaB);
    conv_silu<<<16384, 256, 0, stream>>>(pre, conv_w, fqkv);
    norm_qk<<<4096, 256, 0, stream>>>(fqkv);

    prep_chunk<<<256, 256, 0, stream>>>(fqkv, betaB, lalphaB, Tw, Mw, QTw, KTw, bgam, gamC);
    solve_chunk<<<512, 128, 0, stream>>>(fqkv, betaB, bgam, Tw, WTw, Bw);
    chunk_scan<<<64, 256, 0, stream>>>(Bw, WTw, KTw, QTw, Mw, gamC, ctx);

    epilogue_k<<<4096, 256, 0, stream>>>(ctx, pre, rms_w, yb);
    gemm_bt<<<dim3(16, 8), 256, 0, stream>>>(yb, woutb, outp, 2048, 2048);
}

// Round 5
// 355.392 us; speedup vs baseline: 2.0698x; 1.1751x over previous
//
#include <hip/hip_runtime.h>

#define AS1 __attribute__((address_space(1)))
#define AS3 __attribute__((address_space(3)))

typedef _Float16 f16x8 __attribute__((ext_vector_type(8)));
typedef _Float16 f16x4 __attribute__((ext_vector_type(4)));
typedef _Float16 f16x2 __attribute__((ext_vector_type(2)));
typedef float f32x4 __attribute__((ext_vector_type(4)));

#define MFMA16(a, b, c) __builtin_amdgcn_mfma_f32_16x16x32_f16((a), (b), (c), 0, 0, 0)

// ---------------------------------------------------------------- helpers
__device__ __forceinline__ float silu_f(float v) { return v / (1.f + expf(-v)); }

__device__ __forceinline__ void gload_lds16(const void* g, void* l) {
    __builtin_amdgcn_global_load_lds((AS1 void*)g, (AS3 void*)l, 16, 0, 0);
}

// ---------------------------------------------------------------- f32 -> f16 convert
__global__ void cvt_f16(const float* __restrict__ in, _Float16* __restrict__ out, int n) {
    int i = (blockIdx.x * blockDim.x + threadIdx.x) * 4;
    if (i >= n) return;
    float4 v = *(const float4*)&in[i];
    f16x4 h = { (_Float16)v.x, (_Float16)v.y, (_Float16)v.z, (_Float16)v.w };
    *(f16x4*)&out[i] = h;
}

__global__ void zero_f32(float* __restrict__ p, int n) {
    int i = (blockIdx.x * blockDim.x + threadIdx.x) * 4;
    if (i >= n) return;
    float4 z = {0.f, 0.f, 0.f, 0.f};
    *(float4*)&p[i] = z;
}

// ---------------------------------------------------------------- GEMM: C = A * B^T
__global__ __launch_bounds__(256) void gemm_bt(const _Float16* __restrict__ A,
                                               const _Float16* __restrict__ B,
                                               float* __restrict__ C, int N, int K) {
    __shared__ _Float16 As[128 * 32];
    __shared__ _Float16 Bs[128 * 32];
    const int tid = threadIdx.x;
    const int rowA0 = blockIdx.y * 128, rowB0 = blockIdx.x * 128;
    const int lane = tid & 63;
    const int wave = tid >> 6;
    const int wr = (wave >> 1) * 64, wc = (wave & 1) * 64;
    const int fr = lane & 15, kof = (lane >> 4) * 8;
    const int sr0 = tid >> 2;
    const int sc0 = (tid & 3) * 8;

    f32x4 zero = {0.f, 0.f, 0.f, 0.f};
    f32x4 acc[4][4];
#pragma unroll
    for (int i = 0; i < 4; i++)
#pragma unroll
        for (int j = 0; j < 4; j++) acc[i][j] = zero;

    const _Float16* Abase = A + (long)(rowA0 + sr0) * K + sc0;
    const _Float16* Bbase = B + (long)(rowB0 + sr0) * K + sc0;
    const long chunk2 = (long)64 * K;

    for (int k0 = 0; k0 < K; k0 += 32) {
        __syncthreads();
        gload_lds16(Abase + k0,          &As[tid * 8]);
        gload_lds16(Abase + k0 + chunk2, &As[2048 + tid * 8]);
        gload_lds16(Bbase + k0,          &Bs[tid * 8]);
        gload_lds16(Bbase + k0 + chunk2, &Bs[2048 + tid * 8]);
        __syncthreads();
        f16x8 af[4], bf[4];
#pragma unroll
        for (int mi = 0; mi < 4; mi++) af[mi] = *(const f16x8*)&As[(wr + mi * 16 + fr) * 32 + kof];
#pragma unroll
        for (int ni = 0; ni < 4; ni++) bf[ni] = *(const f16x8*)&Bs[(wc + ni * 16 + fr) * 32 + kof];
#pragma unroll
        for (int mi = 0; mi < 4; mi++)
#pragma unroll
            for (int ni = 0; ni < 4; ni++)
                acc[mi][ni] = MFMA16(af[mi], bf[ni], acc[mi][ni]);
    }
    const int rbase = (lane >> 4) * 4;
#pragma unroll
    for (int mi = 0; mi < 4; mi++)
#pragma unroll
        for (int ni = 0; ni < 4; ni++) {
            int row = rowA0 + wr + mi * 16 + rbase;
            int col = rowB0 + wc + ni * 16 + fr;
#pragma unroll
            for (int r = 0; r < 4; r++)
                C[(long)(row + r) * N + col] = acc[mi][ni][r];
        }
}

// Split-K variant: accumulates into C with atomics (C must be pre-zeroed).
__global__ __launch_bounds__(256) void gemm_bt_sk(const _Float16* __restrict__ A,
                                                  const _Float16* __restrict__ B,
                                                  float* __restrict__ C, int N, int K,
                                                  int KS) {
    __shared__ _Float16 As[128 * 32];
    __shared__ _Float16 Bs[128 * 32];
    const int tid = threadIdx.x;
    const int rowA0 = blockIdx.y * 128, rowB0 = blockIdx.x * 128;
    const int kOff = blockIdx.z * KS;
    const int lane = tid & 63;
    const int wave = tid >> 6;
    const int wr = (wave >> 1) * 64, wc = (wave & 1) * 64;
    const int fr = lane & 15, kof = (lane >> 4) * 8;
    const int sr0 = tid >> 2;
    const int sc0 = (tid & 3) * 8;

    f32x4 zero = {0.f, 0.f, 0.f, 0.f};
    f32x4 acc[4][4];
#pragma unroll
    for (int i = 0; i < 4; i++)
#pragma unroll
        for (int j = 0; j < 4; j++) acc[i][j] = zero;

    const _Float16* Abase = A + (long)(rowA0 + sr0) * K + sc0 + kOff;
    const _Float16* Bbase = B + (long)(rowB0 + sr0) * K + sc0 + kOff;
    const long chunk2 = (long)64 * K;

    for (int k0 = 0; k0 < KS; k0 += 32) {
        __syncthreads();
        gload_lds16(Abase + k0,          &As[tid * 8]);
        gload_lds16(Abase + k0 + chunk2, &As[2048 + tid * 8]);
        gload_lds16(Bbase + k0,          &Bs[tid * 8]);
        gload_lds16(Bbase + k0 + chunk2, &Bs[2048 + tid * 8]);
        __syncthreads();
        f16x8 af[4], bf[4];
#pragma unroll
        for (int mi = 0; mi < 4; mi++) af[mi] = *(const f16x8*)&As[(wr + mi * 16 + fr) * 32 + kof];
#pragma unroll
        for (int ni = 0; ni < 4; ni++) bf[ni] = *(const f16x8*)&Bs[(wc + ni * 16 + fr) * 32 + kof];
#pragma unroll
        for (int mi = 0; mi < 4; mi++)
#pragma unroll
            for (int ni = 0; ni < 4; ni++)
                acc[mi][ni] = MFMA16(af[mi], bf[ni], acc[mi][ni]);
    }
    const int rbase = (lane >> 4) * 4;
#pragma unroll
    for (int mi = 0; mi < 4; mi++)
#pragma unroll
        for (int ni = 0; ni < 4; ni++) {
            int row = rowA0 + wr + mi * 16 + rbase;
            int col = rowB0 + wc + ni * 16 + fr;
#pragma unroll
            for (int r = 0; r < 4; r++)
                unsafeAtomicAdd(&C[(long)(row + r) * N + col], acc[mi][ni][r]);
        }
}

// ---------------------------------------------------------------- beta / log-alpha projections
__global__ __launch_bounds__(256) void proj_ba(const float* __restrict__ x,
                                               const float* __restrict__ w_beta,
                                               const float* __restrict__ w_alpha,
                                               const float* __restrict__ log_A,
                                               const float* __restrict__ dt_bias,
                                               float* __restrict__ betaB,
                                               float* __restrict__ lalphaB) {
    __shared__ float xs[2048];
    const int s = blockIdx.x, tid = threadIdx.x;
    *(float4*)&xs[tid * 8]     = *(const float4*)&x[(long)s * 2048 + tid * 8];
    *(float4*)&xs[tid * 8 + 4] = *(const float4*)&x[(long)s * 2048 + tid * 8 + 4];
    __syncthreads();
    const int o = tid >> 3, j = tid & 7;
    const float* w = (o < 16) ? &w_beta[(long)o * 2048] : &w_alpha[(long)(o - 16) * 2048];
    float p = 0.f;
#pragma unroll 4
    for (int i = 0; i < 64; i++) {
        int d = i * 32 + j * 4;
        float4 wv = *(const float4*)&w[d];
        p += xs[d] * wv.x + xs[d + 1] * wv.y + xs[d + 2] * wv.z + xs[d + 3] * wv.w;
    }
    p += __shfl_xor(p, 1); p += __shfl_xor(p, 2); p += __shfl_xor(p, 4);
    if (j == 0) {
        if (o < 16) {
            betaB[s * 16 + o] = 1.f / (1.f + expf(-p));
        } else {
            int h = o - 16;
            float t = p + dt_bias[h];
            float sp = (t > 20.f) ? t : log1pf(expf(t));
            lalphaB[s * 16 + h] = -expf(log_A[h]) * sp;
        }
    }
}

// ---------------------------------------------------------------- causal depthwise conv(K=4) + SiLU
__global__ void conv_silu(const float* __restrict__ pre, const float* __restrict__ cw,
                          float* __restrict__ outp) {
    int i = blockIdx.x * blockDim.x + threadIdx.x;
    int s = i >> 12, c = i & 4095;
    float4 w = *(const float4*)&cw[c * 4];
    float acc = pre[(long)s * 6144 + c] * w.w;
    if (s >= 1) acc += pre[(long)(s - 1) * 6144 + c] * w.z;
    if (s >= 2) acc += pre[(long)(s - 2) * 6144 + c] * w.y;
    if (s >= 3) acc += pre[(long)(s - 3) * 6144 + c] * w.x;
    outp[i] = silu_f(acc);
}

// ---------------------------------------------------------------- in-place l2 norm of q,k
__global__ void norm_qk(float* __restrict__ fqkv) {
    int gw = (blockIdx.x * blockDim.x + threadIdx.x) >> 6;
    int lane = threadIdx.x & 63;
    int s = gw >> 4, idx = gw & 15;
    float* base = fqkv + (long)s * 4096 + (idx < 8 ? idx * 128 : 1024 + (idx - 8) * 128);
    float2 v = *(float2*)&base[lane * 2];
    float ss = v.x * v.x + v.y * v.y;
#pragma unroll
    for (int m = 1; m < 64; m <<= 1) ss += __shfl_xor(ss, m);
    float sc = rsqrtf(ss + 1e-6f);
    if (idx < 8) sc *= 0.08838834764831843f;  // 1/sqrt(128), queries only
    v.x *= sc; v.y *= sc;
    *(float2*)&base[lane * 2] = v;
}

// ---------------------------------------------------------------- chunked delta rule: precompute
__global__ __launch_bounds__(256) void prep_chunk(const float* __restrict__ fqkv,
                                                  const float* __restrict__ betaB,
                                                  const float* __restrict__ lalphaB,
                                                  _Float16* __restrict__ Tw,
                                                  _Float16* __restrict__ Mw,
                                                  _Float16* __restrict__ QTw,
                                                  _Float16* __restrict__ KTw,
                                                  float* __restrict__ bgam,
                                                  float* __restrict__ gamC) {
    __shared__ _Float16 Kh[64 * 128];
    __shared__ _Float16 Qh[64 * 128];
    __shared__ float lg[64], bet[64];
    const int hc = blockIdx.x;
    const int h = hc >> 4, c = hc & 15, hq = h >> 1, s0 = c * 64;
    const int tid = threadIdx.x;
    if (tid < 64) {
        float la = lalphaB[(s0 + tid) * 16 + h];
#pragma unroll
        for (int d = 1; d < 64; d <<= 1) {
            float t = __shfl_up(la, d, 64);
            if (tid >= d) la += t;
        }
        lg[tid] = la;
        bet[tid] = betaB[(s0 + tid) * 16 + h];
    }
    for (int e = tid; e < 8192; e += 256) {
        int t = e >> 7, m = e & 127;
        Kh[e] = (_Float16)fqkv[(long)(s0 + t) * 4096 + 1024 + hq * 128 + m];
        Qh[e] = (_Float16)fqkv[(long)(s0 + t) * 4096 + hq * 128 + m];
    }
    __syncthreads();
    if (tid < 64) bgam[hc * 64 + tid] = bet[tid] * expf(lg[tid]);
    if (tid == 0) gamC[hc] = expf(lg[63]);
    for (int e = tid; e < 8192; e += 256) {
        int t = e >> 7;
        QTw[(long)hc * 8192 + e] = (_Float16)(expf(lg[t]) * (float)Qh[e]);
    }
    for (int e = tid; e < 8192; e += 256) {
        int m = e >> 6, t = e & 63;
        KTw[(long)hc * 8192 + e] = (_Float16)(expf(lg[63] - lg[t]) * (float)Kh[t * 128 + m]);
    }
    const int wv = tid >> 6, lane = tid & 63, fr = lane & 15, kof = (lane >> 4) * 8, quad = lane >> 4;
    f32x4 accT[4], accM[4];
    f32x4 zero = {0.f, 0.f, 0.f, 0.f};
#pragma unroll
    for (int ci = 0; ci < 4; ci++) { accT[ci] = zero; accM[ci] = zero; }
    for (int k0 = 0; k0 < 128; k0 += 32) {
        f16x8 ak = *(const f16x8*)&Kh[(wv * 16 + fr) * 128 + k0 + kof];
        f16x8 aq = *(const f16x8*)&Qh[(wv * 16 + fr) * 128 + k0 + kof];
#pragma unroll
        for (int ci = 0; ci < 4; ci++) {
            f16x8 bk = *(const f16x8*)&Kh[(ci * 16 + fr) * 128 + k0 + kof];
            accT[ci] = MFMA16(ak, bk, accT[ci]);
            accM[ci] = MFMA16(aq, bk, accM[ci]);
        }
    }
#pragma unroll
    for (int ci = 0; ci < 4; ci++)
#pragma unroll
        for (int r = 0; r < 4; r++) {
            int t = wv * 16 + quad * 4 + r, i = ci * 16 + fr;
            float e = expf(lg[t] - lg[i]);
            Tw[(long)hc * 4096 + t * 64 + i] = (_Float16)((i < t) ? bet[t] * e * accT[ci][r] : 0.f);
            Mw[(long)hc * 4096 + t * 64 + i] = (_Float16)((i <= t) ? e * accM[ci][r] : 0.f);
        }
}

// ---------------------------------------------------------------- blocked forward substitution
// half0: RHS = diag(beta)V -> WT [j][t]; half1: RHS = diag(beta*gamma)K -> Bw [t][m] + BTw [m][t].
__global__ __launch_bounds__(128) void solve_chunk(const float* __restrict__ fqkv,
                                                   const float* __restrict__ betaB,
                                                   const float* __restrict__ bgam,
                                                   const _Float16* __restrict__ Tw,
                                                   _Float16* __restrict__ WTw,
                                                   _Float16* __restrict__ Bw,
                                                   _Float16* __restrict__ BTw) {
    __shared__ float Tl[64 * 64];
    __shared__ float XD[64 * 128];
    const int bid = blockIdx.x;
    const int hc = bid >> 1, half = bid & 1;
    const int h = hc >> 4, c = hc & 15, hq = h >> 1, s0 = c * 64;
    const int j = threadIdx.x;
    for (int e = j; e < 4096; e += 128) Tl[e] = (float)Tw[(long)hc * 4096 + e];
    __syncthreads();
    float Xa[16];
    for (int a = 0; a < 4; ++a) {
#pragma unroll
        for (int r = 0; r < 16; ++r) {
            int t = a * 16 + r;
            float rv;
            if (half == 0)
                rv = betaB[(s0 + t) * 16 + h] * fqkv[(long)(s0 + t) * 4096 + 2048 + h * 128 + j];
            else
                rv = bgam[hc * 64 + t] * fqkv[(long)(s0 + t) * 4096 + 1024 + hq * 128 + j];
            Xa[r] = rv;
        }
        for (int b = 0; b < a; ++b)
            for (int k = 0; k < 16; ++k) {
                float xk = XD[(b * 16 + k) * 128 + j];
#pragma unroll
                for (int r = 0; r < 16; ++r)
                    Xa[r] -= Tl[(a * 16 + r) * 64 + b * 16 + k] * xk;
            }
#pragma unroll
        for (int tp = 0; tp < 16; ++tp) {
            float xt = Xa[tp];
#pragma unroll
            for (int sp = 0; sp < 16; ++sp)
                if (sp > tp) Xa[sp] -= Tl[(a * 16 + sp) * 64 + a * 16 + tp] * xt;
        }
#pragma unroll
        for (int r = 0; r < 16; ++r) XD[(a * 16 + r) * 128 + j] = Xa[r];
    }
    __syncthreads();
    if (half == 0) {
        for (int t = 0; t < 64; ++t)
            WTw[((long)hc * 128 + j) * 64 + t] = (_Float16)XD[t * 128 + j];
    } else {
        for (int t = 0; t < 64; ++t) {
            _Float16 v = (_Float16)XD[t * 128 + j];
            Bw[(long)hc * 8192 + t * 128 + j] = v;
            BTw[((long)hc * 128 + j) * 64 + t] = v;
        }
    }
}

// ---------------------------------------------------------------- G = K~^T B (f16), Rt = (K~^T W)^T (f32)
__global__ __launch_bounds__(256) void gr_kernel(const _Float16* __restrict__ KTw,
                                                 const _Float16* __restrict__ BTw,
                                                 const _Float16* __restrict__ WTw,
                                                 _Float16* __restrict__ Gw,
                                                 float* __restrict__ Rtw) {
    __shared__ _Float16 KTl[128 * 72], BTl[128 * 72], WTl[128 * 72];
    const long hc = blockIdx.x;
    const int tid = threadIdx.x;
    {
        int r = tid >> 1, c0 = (tid & 1) * 32;
        const _Float16* k_ = &KTw[hc * 8192 + r * 64 + c0];
        const _Float16* b_ = &BTw[hc * 8192 + r * 64 + c0];
        const _Float16* w_ = &WTw[hc * 8192 + r * 64 + c0];
#pragma unroll
        for (int i = 0; i < 4; i++) {
            *(f16x8*)&KTl[r * 72 + c0 + i * 8] = *(const f16x8*)&k_[i * 8];
            *(f16x8*)&BTl[r * 72 + c0 + i * 8] = *(const f16x8*)&b_[i * 8];
            *(f16x8*)&WTl[r * 72 + c0 + i * 8] = *(const f16x8*)&w_[i * 8];
        }
    }
    __syncthreads();
    const int wv = tid >> 6, lane = tid & 63;
    const int fr = lane & 15, kof = (lane >> 4) * 8, quad = lane >> 4;
    f32x4 zero = {0.f, 0.f, 0.f, 0.f};
#pragma unroll
    for (int mi = 0; mi < 2; mi++) {
        int m0 = (wv * 2 + mi) * 16;
        f16x8 a0 = *(const f16x8*)&KTl[(m0 + fr) * 72 + kof];
        f16x8 a1 = *(const f16x8*)&KTl[(m0 + fr) * 72 + 32 + kof];
#pragma unroll
        for (int nj = 0; nj < 8; nj++) {
            f32x4 acc = zero;
            acc = MFMA16(a0, *(const f16x8*)&BTl[(nj * 16 + fr) * 72 + kof], acc);
            acc = MFMA16(a1, *(const f16x8*)&BTl[(nj * 16 + fr) * 72 + 32 + kof], acc);
#pragma unroll
            for (int r = 0; r < 4; r++)
                Gw[hc * 16384 + (long)(m0 + quad * 4 + r) * 128 + nj * 16 + fr] = (_Float16)acc[r];
        }
    }
#pragma unroll
    for (int ji = 0; ji < 2; ji++) {
        int j0 = (wv * 2 + ji) * 16;
        f16x8 a0 = *(const f16x8*)&WTl[(j0 + fr) * 72 + kof];
        f16x8 a1 = *(const f16x8*)&WTl[(j0 + fr) * 72 + 32 + kof];
#pragma unroll
        for (int nm = 0; nm < 8; nm++) {
            f32x4 acc = zero;
            acc = MFMA16(a0, *(const f16x8*)&KTl[(nm * 16 + fr) * 72 + kof], acc);
            acc = MFMA16(a1, *(const f16x8*)&KTl[(nm * 16 + fr) * 72 + 32 + kof], acc);
#pragma unroll
            for (int r = 0; r < 4; r++)
                Rtw[hc * 16384 + (long)(j0 + quad * 4 + r) * 128 + nm * 16 + fr] = acc[r];
        }
    }
}

// ---------------------------------------------------------------- serial affine state scan
// Z = S^T slice (32 dv-rows x 128 dk). Z' = gC*Z - Z.G^T + Rt. Dumps entering state per chunk.
__global__ __launch_bounds__(256) void serial_scan(const _Float16* __restrict__ Gw,
                                                   const float* __restrict__ Rtw,
                                                   const float* __restrict__ gamC,
                                                   float* __restrict__ Zdump) {
    __shared__ _Float16 Zhi[32 * 136], Zlo[32 * 136];
    __shared__ _Float16 Gl[128 * 136];
    const int tid = threadIdx.x;
    const int h = blockIdx.x >> 2, js = (blockIdx.x & 3) * 32;
    const int wv = tid >> 6, lane = tid & 63;
    const int fr = lane & 15, kof = (lane >> 4) * 8, quad = lane >> 4;
    const int gr_ = tid >> 1, gc_ = (tid & 1) * 64;   // each thread owns 64 cols of one G row

    for (int e = tid; e < 32 * 136; e += 256) { Zhi[e] = (_Float16)0.f; Zlo[e] = (_Float16)0.f; }
    float z[2][2][4];
#pragma unroll
    for (int jt = 0; jt < 2; jt++)
#pragma unroll
        for (int u = 0; u < 2; u++)
#pragma unroll
            for (int r = 0; r < 4; r++) z[jt][u][r] = 0.f;

    long hc0 = (long)h * 16;
    f16x8 gpre[8];
#pragma unroll
    for (int i = 0; i < 8; i++)
        gpre[i] = *(const f16x8*)&Gw[hc0 * 16384 + (long)gr_ * 128 + gc_ + i * 8];
    float rpre[2][2][4];
#pragma unroll
    for (int jt = 0; jt < 2; jt++)
#pragma unroll
        for (int u = 0; u < 2; u++)
#pragma unroll
            for (int r = 0; r < 4; r++)
                rpre[jt][u][r] = Rtw[hc0 * 16384 +
                                     (long)(js + jt * 16 + quad * 4 + r) * 128 +
                                     (2 * wv + u) * 16 + fr];
    __syncthreads();

    for (int c = 0; c < 16; ++c) {
        long hc = (long)h * 16 + c;
        float gC = gamC[hc];
        // stage G(c) from regs (full 64-col span per thread)
#pragma unroll
        for (int i = 0; i < 8; i++)
            *(f16x8*)&Gl[gr_ * 136 + gc_ + i * 8] = gpre[i];
        // prefetch c+1
        long hcn = (long)h * 16 + (c < 15 ? c + 1 : 15);
        f16x8 gnext[8];
#pragma unroll
        for (int i = 0; i < 8; i++)
            gnext[i] = *(const f16x8*)&Gw[hcn * 16384 + (long)gr_ * 128 + gc_ + i * 8];
        float rnext[2][2][4];
#pragma unroll
        for (int jt = 0; jt < 2; jt++)
#pragma unroll
            for (int u = 0; u < 2; u++)
#pragma unroll
                for (int r = 0; r < 4; r++)
                    rnext[jt][u][r] = Rtw[hcn * 16384 +
                                          (long)(js + jt * 16 + quad * 4 + r) * 128 +
                                          (2 * wv + u) * 16 + fr];
        __syncthreads();
        // MFMA: acc[jt][u] = sum_{m'} Z[j][m'] G[m][m']
        f32x4 acc[2][2];
        f32x4 zero = {0.f, 0.f, 0.f, 0.f};
#pragma unroll
        for (int jt = 0; jt < 2; jt++)
#pragma unroll
            for (int u = 0; u < 2; u++) acc[jt][u] = zero;
        for (int k0 = 0; k0 < 128; k0 += 32) {
            f16x8 ahi[2], alo[2], bfr[2];
#pragma unroll
            for (int jt = 0; jt < 2; jt++) {
                ahi[jt] = *(const f16x8*)&Zhi[(jt * 16 + fr) * 136 + k0 + kof];
                alo[jt] = *(const f16x8*)&Zlo[(jt * 16 + fr) * 136 + k0 + kof];
            }
#pragma unroll
            for (int u = 0; u < 2; u++)
                bfr[u] = *(const f16x8*)&Gl[((2 * wv + u) * 16 + fr) * 136 + k0 + kof];
#pragma unroll
            for (int jt = 0; jt < 2; jt++)
#pragma unroll
                for (int u = 0; u < 2; u++) {
                    acc[jt][u] = MFMA16(ahi[jt], bfr[u], acc[jt][u]);
                    acc[jt][u] = MFMA16(alo[jt], bfr[u], acc[jt][u]);
                }
        }
        __syncthreads();
        // epilogue: dump old (entering) state, then update
#pragma unroll
        for (int jt = 0; jt < 2; jt++)
#pragma unroll
            for (int u = 0; u < 2; u++)
#pragma unroll
                for (int r = 0; r < 4; r++) {
                    int j = jt * 16 + quad * 4 + r;
                    int m = (2 * wv + u) * 16 + fr;
                    Zdump[hc * 16384 + (long)(js + j) * 128 + m] = z[jt][u][r];
                    float zn = gC * z[jt][u][r] - acc[jt][u][r] + rpre[jt][u][r];
                    z[jt][u][r] = zn;
                    _Float16 hi = (_Float16)zn;
                    Zhi[j * 136 + m] = hi;
                    Zlo[j * 136 + m] = (_Float16)(zn - (float)hi);
                }
#pragma unroll
        for (int i = 0; i < 8; i++) gpre[i] = gnext[i];
#pragma unroll
        for (int jt = 0; jt < 2; jt++)
#pragma unroll
            for (int u = 0; u < 2; u++)
#pragma unroll
                for (int r = 0; r < 4; r++) rpre[jt][u][r] = rnext[jt][u][r];
    }
}

// ---------------------------------------------------------------- per-chunk output (parallel)
__global__ __launch_bounds__(256) void out_chunk(const float* __restrict__ Zdump,
                                                 const _Float16* __restrict__ Bw,
                                                 const _Float16* __restrict__ WTw,
                                                 const _Float16* __restrict__ QTw,
                                                 const _Float16* __restrict__ Mw,
                                                 float* __restrict__ ctx) {
    __shared__ _Float16 SThi[64 * 136], STlo[64 * 136], Bl[64 * 136];
    __shared__ _Float16 UT[64 * 72];
    const int bid = blockIdx.x;
    const long hc = bid >> 1;
    const int jh = (bid & 1) * 64;
    const int h = (int)(hc >> 4), c = (int)(hc & 15), s0 = c * 64;
    const int tid = threadIdx.x, wv = tid >> 6, lane = tid & 63;
    const int fr = lane & 15, kof = (lane >> 4) * 8, quad = lane >> 4;
    {
        int r = tid >> 2, c0 = (tid & 3) * 32;
        const float* src = &Zdump[hc * 16384 + (long)(jh + r) * 128 + c0];
#pragma unroll
        for (int i = 0; i < 8; i++) {
            float4 v = *(const float4*)&src[i * 4];
            _Float16 h0 = (_Float16)v.x, h1 = (_Float16)v.y, h2 = (_Float16)v.z, h3 = (_Float16)v.w;
            f16x4 hi = {h0, h1, h2, h3};
            f16x4 lo = {(_Float16)(v.x - (float)h0), (_Float16)(v.y - (float)h1),
                        (_Float16)(v.z - (float)h2), (_Float16)(v.w - (float)h3)};
            *(f16x4*)&SThi[r * 136 + c0 + i * 4] = hi;
            *(f16x4*)&STlo[r * 136 + c0 + i * 4] = lo;
        }
        const _Float16* bsrc = &Bw[hc * 8192 + r * 128 + c0];
#pragma unroll
        for (int i = 0; i < 4; i++)
            *(f16x8*)&Bl[r * 136 + c0 + i * 8] = *(const f16x8*)&bsrc[i * 8];
    }
    __syncthreads();
    const int t0 = wv * 16;
    // phase 1: U
    f16x8 ba[4];
#pragma unroll
    for (int k = 0; k < 4; k++)
        ba[k] = *(const f16x8*)&Bl[(t0 + fr) * 136 + k * 32 + kof];
#pragma unroll
    for (int jt = 0; jt < 4; jt++) {
        f32x4 acc = {0.f, 0.f, 0.f, 0.f};
#pragma unroll
        for (int k = 0; k < 4; k++) {
            acc = MFMA16(ba[k], *(const f16x8*)&SThi[(jt * 16 + fr) * 136 + k * 32 + kof], acc);
            acc = MFMA16(ba[k], *(const f16x8*)&STlo[(jt * 16 + fr) * 136 + k * 32 + kof], acc);
        }
#pragma unroll
        for (int r = 0; r < 4; r++) {
            int t = t0 + quad * 4 + r;
            int j = jt * 16 + fr;
            float w = (float)WTw[hc * 8192 + (long)(jh + j) * 64 + t];
            UT[j * 72 + t] = (_Float16)(w - acc[r]);
        }
    }
    __syncthreads();
    // phase 2: O
    f16x8 qa[4], ma[2];
#pragma unroll
    for (int k = 0; k < 4; k++)
        qa[k] = *(const f16x8*)&QTw[hc * 8192 + (long)(t0 + fr) * 128 + k * 32 + kof];
#pragma unroll
    for (int k = 0; k < 2; k++)
        ma[k] = *(const f16x8*)&Mw[hc * 4096 + (long)(t0 + fr) * 64 + k * 32 + kof];
#pragma unroll
    for (int jt = 0; jt < 4; jt++) {
        f32x4 acc = {0.f, 0.f, 0.f, 0.f};
#pragma unroll
        for (int k = 0; k < 4; k++) {
            acc = MFMA16(qa[k], *(const f16x8*)&SThi[(jt * 16 + fr) * 136 + k * 32 + kof], acc);
            acc = MFMA16(qa[k], *(const f16x8*)&STlo[(jt * 16 + fr) * 136 + k * 32 + kof], acc);
        }
#pragma unroll
        for (int k = 0; k < 2; k++)
            acc = MFMA16(ma[k], *(const f16x8*)&UT[(jt * 16 + fr) * 72 + k * 32 + kof], acc);
#pragma unroll
        for (int r = 0; r < 4; r++) {
            int t = t0 + quad * 4 + r;
            int j = jt * 16 + fr;
            ctx[(long)(s0 + t) * 2048 + h * 128 + jh + j] = acc[r];
        }
    }
}

// ---------------------------------------------------------------- rms_norm(ctx)*rms_w * silu(gate) -> f16
__global__ void epilogue_k(const float* __restrict__ ctx, const float* __restrict__ pre,
                           const float* __restrict__ rms_w, _Float16* __restrict__ y) {
    int gw = (blockIdx.x * blockDim.x + threadIdx.x) >> 6;
    int lane = threadIdx.x & 63;
    int s = gw >> 4, h = gw & 15;
    long base = (long)s * 2048 + h * 128;
    long gbase = (long)s * 6144 + 4096 + h * 128;
    float2 cv = *(const float2*)&ctx[base + lane * 2];
    float ss = cv.x * cv.x + cv.y * cv.y;
#pragma unroll
    for (int m = 1; m < 64; m <<= 1) ss += __shfl_xor(ss, m);
    float sc = rsqrtf(ss * (1.f / 128.f) + 1e-6f);
    int d = lane * 2;
    float2 rw = *(const float2*)&rms_w[d];
    float g0 = silu_f(pre[gbase + d]);
    float g1 = silu_f(pre[gbase + d + 1]);
    f16x2 hv = { (_Float16)(cv.x * sc * rw.x * g0), (_Float16)(cv.y * sc * rw.y * g1) };
    *(f16x2*)&y[base + d] = hv;
}

// ---------------------------------------------------------------- launch
extern "C" void kernel_launch(void* const* d_in, const int* in_sizes, int n_in,
                              void* d_out, int out_size, void* d_ws, size_t ws_size,
                              hipStream_t stream) {
    const float* x       = (const float*)d_in[0];
    const float* w_qkv   = (const float*)d_in[1];
    const float* w_gate  = (const float*)d_in[2];
    const float* w_beta  = (const float*)d_in[3];
    const float* w_alpha = (const float*)d_in[4];
    const float* log_A   = (const float*)d_in[5];
    const float* dt_bias = (const float*)d_in[6];
    const float* conv_w  = (const float*)d_in[7];
    const float* rms_w   = (const float*)d_in[8];
    const float* w_out   = (const float*)d_in[9];
    float* outp = (float*)d_out;

    char* ws = (char*)d_ws;
    size_t off = 0;
    _Float16* xb     = (_Float16*)(ws + off); off += (size_t)1024 * 2048 * 2;
    _Float16* wfused = (_Float16*)(ws + off); off += (size_t)6144 * 2048 * 2;
    _Float16* woutb  = (_Float16*)(ws + off); off += (size_t)2048 * 2048 * 2;
    _Float16* yb     = (_Float16*)(ws + off); off += (size_t)1024 * 2048 * 2;
    float* pre       = (float*)(ws + off);    off += (size_t)1024 * 6144 * 4;
    float* fqkv      = (float*)(ws + off);    off += (size_t)1024 * 4096 * 4;
    float* ctx       = (float*)(ws + off);    off += (size_t)1024 * 16 * 128 * 4;
    float* betaB     = (float*)(ws + off);    off += (size_t)1024 * 16 * 4;
    float* lalphaB   = (float*)(ws + off);    off += (size_t)1024 * 16 * 4;
    _Float16* Tw     = (_Float16*)(ws + off); off += (size_t)256 * 4096 * 2;
    _Float16* Mw     = (_Float16*)(ws + off); off += (size_t)256 * 4096 * 2;
    _Float16* QTw    = (_Float16*)(ws + off); off += (size_t)256 * 8192 * 2;
    _Float16* KTw    = (_Float16*)(ws + off); off += (size_t)256 * 8192 * 2;
    _Float16* WTw    = (_Float16*)(ws + off); off += (size_t)256 * 8192 * 2;
    _Float16* Bw     = (_Float16*)(ws + off); off += (size_t)256 * 8192 * 2;
    _Float16* BTw    = (_Float16*)(ws + off); off += (size_t)256 * 8192 * 2;
    float* bgam      = (float*)(ws + off);    off += (size_t)256 * 64 * 4;
    float* gamC      = (float*)(ws + off);    off += (size_t)256 * 4;
    _Float16* Gw     = (_Float16*)(ws + off); off += (size_t)256 * 16384 * 2;
    float* Rtw       = (float*)(ws + off);    off += (size_t)256 * 16384 * 4;
    // Zdump aliases fqkv: fqkv's last reader is solve_chunk; serial_scan
    // (producer of Zdump) runs strictly after it on the same stream.
    float* Zdump     = fqkv;

    cvt_f16<<<2048, 256, 0, stream>>>(x, xb, 1024 * 2048);
    cvt_f16<<<8192, 256, 0, stream>>>(w_qkv, wfused, 4096 * 2048);
    cvt_f16<<<4096, 256, 0, stream>>>(w_gate, wfused + (size_t)4096 * 2048, 2048 * 2048);
    cvt_f16<<<4096, 256, 0, stream>>>(w_out, woutb, 2048 * 2048);

    gemm_bt<<<dim3(48, 8), 256, 0, stream>>>(xb, wfused, pre, 6144, 2048);
    proj_ba<<<1024, 256, 0, stream>>>(x, w_beta, w_alpha, log_A, dt_bias, betaB, lalphaB);
    conv_silu<<<16384, 256, 0, stream>>>(pre, conv_w, fqkv);
    norm_qk<<<4096, 256, 0, stream>>>(fqkv);

    prep_chunk<<<256, 256, 0, stream>>>(fqkv, betaB, lalphaB, Tw, Mw, QTw, KTw, bgam, gamC);
    solve_chunk<<<512, 128, 0, stream>>>(fqkv, betaB, bgam, Tw, WTw, Bw, BTw);
    gr_kernel<<<256, 256, 0, stream>>>(KTw, BTw, WTw, Gw, Rtw);
    serial_scan<<<64, 256, 0, stream>>>(Gw, Rtw, gamC, Zdump);
    out_chunk<<<512, 256, 0, stream>>>(Zdump, Bw, WTw, QTw, Mw, ctx);

    epilogue_k<<<4096, 256, 0, stream>>>(ctx, pre, rms_w, yb);
    zero_f32<<<2048, 256, 0, stream>>>(outp, 1024 * 2048);
    gemm_bt_sk<<<dim3(16, 8, 2), 256, 0, stream>>>(yb, woutb, outp, 2048, 2048, 1024);
}